// Round 4
// baseline (287.498 us; speedup 1.0000x reference)
//
#include <hip/hip_runtime.h>
#include <stdint.h>
#include <math.h>

typedef __bf16 bf16;
typedef __bf16 bf16x4 __attribute__((ext_vector_type(4)));
typedef __bf16 bf16x8 __attribute__((ext_vector_type(8)));
typedef float  f32x4  __attribute__((ext_vector_type(4)));

#define B_DIM 8192
#define K_DIM 4096
#define N_DIM 4096
#define MEM_H 1048576
#define HMOD  1047552   // MEM_H - 32*32
#define NT    (K_DIM / 64)

// ---------------- host-side numpy legacy RNG replication ----------------
static void mt_randint3(uint32_t seed, long long R[3]) {
  uint32_t mt[624];
  mt[0] = seed;
  for (int i = 1; i < 624; i++)
    mt[i] = 1812433253u * (mt[i - 1] ^ (mt[i - 1] >> 30)) + (uint32_t)i;
  int pos = 624;
  auto next32 = [&]() -> uint32_t {
    if (pos >= 624) {
      for (int i = 0; i < 624; i++) {
        uint32_t y = (mt[i] & 0x80000000u) | (mt[(i + 1) % 624] & 0x7fffffffu);
        uint32_t v = mt[(i + 397) % 624] ^ (y >> 1);
        if (y & 1u) v ^= 0x9908b0dfu;
        mt[i] = v;
      }
      pos = 0;
    }
    uint32_t y = mt[pos++];
    y ^= y >> 11;
    y ^= (y << 7) & 0x9d2c5680u;
    y ^= (y << 15) & 0xefc60000u;
    y ^= y >> 18;
    return y;
  };
  for (int j = 0; j < 3; j++) {
    uint32_t v;
    do { v = next32() & 0x7fffffffu; } while (v > 0x7ffffffdu);
    R[j] = 1LL + (long long)v;
  }
}

// ---------------- x: f32 -> bf16 (vectorized) ----------------
__global__ void k_convert_x(const float* __restrict__ x, bf16* __restrict__ xb) {
  int i = blockIdx.x * 256 + threadIdx.x;
  const f32x4* p = (const f32x4*)x;
  f32x4 a = p[2 * i], b = p[2 * i + 1];
  bf16x8 o;
  o[0] = (bf16)a[0]; o[1] = (bf16)a[1]; o[2] = (bf16)a[2]; o[3] = (bf16)a[3];
  o[4] = (bf16)b[0]; o[5] = (bf16)b[1]; o[6] = (bf16)b[2]; o[7] = (bf16)b[3];
  ((bf16x8*)xb)[i] = o;
}

// ---------------- build W^T [N][K] bf16 from hashed vector ----------------
__global__ void k_build_wt(const float* __restrict__ hw, bf16* __restrict__ wt,
                           long long R1, long long R2, long long R3) {
  int tile = blockIdx.x;
  int kb = tile & 127, nb = tile >> 7;
  long long v = (long long)kb * R3 + (long long)nb * R2 + R1;
  int start = (int)((v % 2147483647LL) % (long long)HMOD);
  const float* src = hw + start;
  int t  = threadIdx.x;
  int nl = t >> 3;
  int k4 = t & 7;
  bf16x4 o;
#pragma unroll
  for (int j = 0; j < 4; j++) o[j] = (bf16)src[(k4 * 4 + j) * 32 + nl];
  *(bf16x4*)(wt + (size_t)(nb * 32 + nl) * K_DIM + kb * 32 + k4 * 4) = o;
}

// ---------------- 256x256x64 8-phase GEMM, deep prefetch pipeline --------
// Sync invariant (the R3 bug): vmcnt is PER-WAVE, and each wave stages only
// its own 8-row slice of each 64-row unit. A counted wait therefore only
// helps if it is placed BEFORE a barrier: each wave drains its own DMA,
// then the barrier makes all waves' landings visible. Never wait at the
// read point.
__device__ __forceinline__ void gload_lds16(const void* g, void* l) {
  __builtin_amdgcn_global_load_lds(
      (const __attribute__((address_space(1))) void*)g,
      (__attribute__((address_space(3))) void*)l, 16, 0, 0);
}

#define ASM_VMCNT(n) asm volatile("s_waitcnt vmcnt(" #n ")" ::: "memory")
#define BAR() asm volatile("s_barrier" ::: "memory")

#define MM(rh, ch) do {                                                        \
  __builtin_amdgcn_s_setprio(1);                                               \
  _Pragma("unroll")                                                            \
  for (int ks = 0; ks < 2; ks++)                                               \
    _Pragma("unroll")                                                          \
    for (int r4 = 0; r4 < 4; r4++)                                             \
      _Pragma("unroll")                                                        \
      for (int c2 = 0; c2 < 2; c2++)                                           \
        acc[(rh)*4 + r4][(ch)*2 + c2] =                                        \
            __builtin_amdgcn_mfma_f32_16x16x32_bf16(                           \
                af[r4][ks], bg[(ch)*2 + c2][ks],                               \
                acc[(rh)*4 + r4][(ch)*2 + c2], 0, 0, 0);                       \
  __builtin_amdgcn_s_setprio(0);                                               \
} while (0)

__global__ __launch_bounds__(512, 2) void k_gemm(const bf16* __restrict__ A,
                                                 const bf16* __restrict__ Bt,
                                                 float* __restrict__ partial) {
  // [buf][op 0=A 1=B][half][128*64] : 128 KiB
  __shared__ bf16 sm[2][2][2][128 * 64];
  int bid = blockIdx.x;
  int swz = (bid & 7) * 64 + (bid >> 3);     // 512 blocks, 8 XCDs, bijective
  int mt = swz & 31, nt = swz >> 5;
  int tid = threadIdx.x;
  int w = tid >> 6, lane = tid & 63;
  int wm = w >> 2, wn = w & 3;               // 2 x 4 wave grid, 128x64 each
  int lr = lane & 15, lk = lane >> 4;
  int r8 = lane >> 3, gg = lane & 7;
  int swcol = ((gg ^ r8) << 3);              // pre-swizzled source col (elems)
  size_t bm = (size_t)mt * 256, bn = (size_t)nt * 256;
  const bf16* Ab = A + bm * K_DIM;
  const bf16* Bb = Bt + bn * K_DIM;

  f32x4 acc[8][4] = {};
  bf16x8 af[4][2], bg[4][2];

  // stage one 64-row unit (64 rows x 64 k); each wave stages rows w*8..w*8+7
  auto STAGE_AU = [&](int q, int tt, int buf) {
    gload_lds16(Ab + (size_t)(q * 64 + w * 8 + r8) * K_DIM + tt * 64 + swcol,
                &sm[buf][0][q >> 1][(q & 1) * 4096 + w * 8 * 64]);
  };
  auto STAGE_BV = [&](int j, int tt, int buf) {
    gload_lds16(Bb + (size_t)(j * 64 + w * 8 + r8) * K_DIM + tt * 64 + swcol,
                &sm[buf][1][j >> 1][(j & 1) * 4096 + w * 8 * 64]);
  };
  // swizzled fragment reads
  auto RDA = [&](int buf, int rb, int ks) -> bf16x8 {
    const bf16* h = &sm[buf][0][wm][0];
    int row = rb * 16 + lr;
    int gc = ks * 4 + lk;
    return *(const bf16x8*)(h + row * 64 + ((gc ^ (row & 7)) << 3));
  };
  auto RDB = [&](int buf, int cb, int ks) -> bf16x8 {
    const bf16* h = &sm[buf][1][wn >> 1][0];
    int row = (wn & 1) * 64 + cb * 16 + lr;
    int gc = ks * 4 + lk;
    return *(const bf16x8*)(h + row * 64 + ((gc ^ (row & 7)) << 3));
  };

  // prologue: issue in steady-state FIFO order (14 loads), then drain to 6
  // (= tile 0's 8 loads landed for ALL waves after the barrier)
  STAGE_AU(0, 0, 0); STAGE_AU(2, 0, 0);    // needed t0 ph0
  STAGE_BV(0, 0, 0); STAGE_BV(1, 0, 0);    // needed t0 ph0
  STAGE_BV(2, 0, 0); STAGE_BV(3, 0, 0);    // needed t0 ph0/ph1
  STAGE_AU(1, 0, 0); STAGE_AU(3, 0, 0);    // needed t0 ph2
  STAGE_AU(0, 1, 1); STAGE_AU(2, 1, 1);    // needed t1 ph0
  STAGE_BV(0, 1, 1); STAGE_BV(1, 1, 1);    // needed t1 ph0
  STAGE_BV(2, 1, 1); STAGE_BV(3, 1, 1);    // needed t1 ph0/ph1
  ASM_VMCNT(6);
  BAR();

  for (int t = 0; t < NT; t++) {
    int cur = t & 1, nxt = cur ^ 1;
    int t1 = (t + 1 < NT) ? t + 1 : NT - 1;  // clamped: keeps vmcnt FIFO uniform
    int t2 = (t + 2 < NT) ? t + 2 : NT - 1;

    // ---- phase 0: reads A u0/u2 + B(all units, rows 0-31 of each) ----
#pragma unroll
    for (int rb = 0; rb < 4; rb++) {
      af[rb][0] = RDA(cur, rb, 0);
      af[rb][1] = RDA(cur, rb, 1);
    }
#pragma unroll
    for (int cb = 0; cb < 2; cb++) {
      bg[cb][0] = RDB(cur, cb, 0);
      bg[cb][1] = RDB(cur, cb, 1);
    }
    STAGE_AU(1, t1, nxt); STAGE_AU(3, t1, nxt);   // regions freed @ph2 of t-1
    BAR();
    MM(0, 0);
    BAR();

    // ---- phase 1: reads B rows 32-63 of each unit ----
#pragma unroll
    for (int cb = 2; cb < 4; cb++) {
      bg[cb][0] = RDB(cur, cb, 0);
      bg[cb][1] = RDB(cur, cb, 1);
    }
    STAGE_AU(0, t2, cur); STAGE_AU(2, t2, cur);   // cur A u0/u2 freed @ph0
    BAR();
    MM(0, 1);
    BAR();

    // ---- phase 2: reads A u1/u3 ----
#pragma unroll
    for (int rb = 0; rb < 4; rb++) {
      af[rb][0] = RDA(cur, 4 + rb, 0);
      af[rb][1] = RDA(cur, 4 + rb, 1);
    }
    STAGE_BV(0, t2, cur); STAGE_BV(1, t2, cur);   // cur B freed @ph1
    BAR();
    MM(1, 0);
    BAR();

    // ---- phase 3: no reads ----
    STAGE_BV(2, t2, cur); STAGE_BV(3, t2, cur);
    BAR();
    MM(1, 1);
    // drain so that after the barrier ALL waves' tile-(t+1) loads are in LDS;
    // the 6 newest (ph1-ph3 stages, all for t+2) may stay in flight.
    ASM_VMCNT(6);
    BAR();
  }
  ASM_VMCNT(0);   // drain dummy tail DMA before endpgm

  // epilogue: per-row sum of squares over this wave's 64 cols
  // C frag: col = cb*16 + (lane&15), row = rb*16 + (lane>>4)*4 + reg
#pragma unroll
  for (int rb = 0; rb < 8; rb++) {
#pragma unroll
    for (int reg = 0; reg < 4; reg++) {
      float s = 0.f;
#pragma unroll
      for (int cb = 0; cb < 4; cb++) { float v = acc[rb][cb][reg]; s += v * v; }
      s += __shfl_xor(s, 1);
      s += __shfl_xor(s, 2);
      s += __shfl_xor(s, 4);
      s += __shfl_xor(s, 8);
      if (lr == 0) {
        int row = (int)bm + wm * 128 + rb * 16 + lk * 4 + reg;
        partial[(size_t)(nt * 4 + wn) * B_DIM + row] = s;
      }
    }
  }
}

// ---------------- finish: sum 64 partials per row, sqrt ----------------
__global__ void k_finish(const float* __restrict__ partial, float* __restrict__ out) {
  int b = blockIdx.x * 256 + threadIdx.x;
  float s = 0.f;
#pragma unroll
  for (int i = 0; i < 64; i++) s += partial[(size_t)i * B_DIM + b];
  out[b] = sqrtf(s);
}

extern "C" void kernel_launch(void* const* d_in, const int* in_sizes, int n_in,
                              void* d_out, int out_size, void* d_ws, size_t ws_size,
                              hipStream_t stream) {
  const float* x  = (const float*)d_in[0];
  const float* hw = (const float*)d_in[1];
  float* out = (float*)d_out;
  char* ws = (char*)d_ws;
  bf16* xb = (bf16*)ws;                                           // 64 MB
  bf16* wt = (bf16*)(ws + (size_t)B_DIM * K_DIM * 2);             // 32 MB
  float* partial = (float*)(ws + (size_t)B_DIM * K_DIM * 2
                               + (size_t)K_DIM * N_DIM * 2);      // 2 MB

  long long R[3];
  mt_randint3(1367u, R);

  k_convert_x<<<(B_DIM * K_DIM) / (256 * 8), 256, 0, stream>>>(x, xb);
  k_build_wt<<<(K_DIM / 32) * (N_DIM / 32), 256, 0, stream>>>(hw, wt, R[0], R[1], R[2]);
  k_gemm<<<(B_DIM / 256) * (N_DIM / 256), 512, 0, stream>>>(xb, wt, partial);
  k_finish<<<B_DIM / 256, 256, 0, stream>>>(partial, out);
}

// Round 6
// 275.161 us; speedup vs baseline: 1.0448x; 1.0448x over previous
//
#include <hip/hip_runtime.h>
#include <stdint.h>
#include <math.h>

typedef __bf16 bf16;
typedef __bf16 bf16x4 __attribute__((ext_vector_type(4)));
typedef __bf16 bf16x8 __attribute__((ext_vector_type(8)));
typedef float  f32x4  __attribute__((ext_vector_type(4)));

#define B_DIM 8192
#define K_DIM 4096
#define N_DIM 4096
#define MEM_H 1048576
#define HMOD  1047552   // MEM_H - 32*32
#define NT    (K_DIM / 64)

// ---------------- host-side numpy legacy RNG replication ----------------
static void mt_randint3(uint32_t seed, long long R[3]) {
  uint32_t mt[624];
  mt[0] = seed;
  for (int i = 1; i < 624; i++)
    mt[i] = 1812433253u * (mt[i - 1] ^ (mt[i - 1] >> 30)) + (uint32_t)i;
  int pos = 624;
  auto next32 = [&]() -> uint32_t {
    if (pos >= 624) {
      for (int i = 0; i < 624; i++) {
        uint32_t y = (mt[i] & 0x80000000u) | (mt[(i + 1) % 624] & 0x7fffffffu);
        uint32_t v = mt[(i + 397) % 624] ^ (y >> 1);
        if (y & 1u) v ^= 0x9908b0dfu;
        mt[i] = v;
      }
      pos = 0;
    }
    uint32_t y = mt[pos++];
    y ^= y >> 11;
    y ^= (y << 7) & 0x9d2c5680u;
    y ^= (y << 15) & 0xefc60000u;
    y ^= y >> 18;
    return y;
  };
  for (int j = 0; j < 3; j++) {
    uint32_t v;
    do { v = next32() & 0x7fffffffu; } while (v > 0x7ffffffdu);
    R[j] = 1LL + (long long)v;
  }
}

// ---------------- x: f32 -> bf16 (vectorized) ----------------
__global__ void k_convert_x(const float* __restrict__ x, bf16* __restrict__ xb) {
  int i = blockIdx.x * 256 + threadIdx.x;
  const f32x4* p = (const f32x4*)x;
  f32x4 a = p[2 * i], b = p[2 * i + 1];
  bf16x8 o;
  o[0] = (bf16)a[0]; o[1] = (bf16)a[1]; o[2] = (bf16)a[2]; o[3] = (bf16)a[3];
  o[4] = (bf16)b[0]; o[5] = (bf16)b[1]; o[6] = (bf16)b[2]; o[7] = (bf16)b[3];
  ((bf16x8*)xb)[i] = o;
}

// ---------------- build W^T [N][K] bf16 from hashed vector ----------------
__global__ void k_build_wt(const float* __restrict__ hw, bf16* __restrict__ wt,
                           long long R1, long long R2, long long R3) {
  int tile = blockIdx.x;
  int kb = tile & 127, nb = tile >> 7;
  long long v = (long long)kb * R3 + (long long)nb * R2 + R1;
  int start = (int)((v % 2147483647LL) % (long long)HMOD);
  const float* src = hw + start;
  int t  = threadIdx.x;
  int nl = t >> 3;
  int k4 = t & 7;
  bf16x4 o;
#pragma unroll
  for (int j = 0; j < 4; j++) o[j] = (bf16)src[(k4 * 4 + j) * 32 + nl];
  *(bf16x4*)(wt + (size_t)(nb * 32 + nl) * K_DIM + kb * 32 + k4 * 4) = o;
}

// ---------------- 256x256x64 GEMM, 4 waves @ 128x128/wave ----------------
// LDS-read-amplification = WARPS_N (A) + WARPS_M (B). 2x2 grid -> 2x.
// Sync skeleton cloned from the verified R4 template (vmcnt-before-barrier
// invariant: vmcnt is per-wave; counted wait must precede a barrier).
// R5 bug fixed here: LDS dest inside STAGE_U must use the row WITHIN the
// 64-row unit (w*16+h8*8), not the global tile row (which includes q*64).
__device__ __forceinline__ void gload_lds16(const void* g, void* l) {
  __builtin_amdgcn_global_load_lds(
      (const __attribute__((address_space(1))) void*)g,
      (__attribute__((address_space(3))) void*)l, 16, 0, 0);
}

#define ASM_VMCNT(n) asm volatile("s_waitcnt vmcnt(" #n ")" ::: "memory")
#define BAR() asm volatile("s_barrier" ::: "memory")

#define MM(rh, ch) do {                                                        \
  __builtin_amdgcn_s_setprio(1);                                               \
  _Pragma("unroll")                                                            \
  for (int ks = 0; ks < 2; ks++)                                               \
    _Pragma("unroll")                                                          \
    for (int r4 = 0; r4 < 4; r4++)                                             \
      _Pragma("unroll")                                                        \
      for (int c4 = 0; c4 < 4; c4++)                                           \
        acc[(rh)*4 + r4][(ch)*4 + c4] =                                        \
            __builtin_amdgcn_mfma_f32_16x16x32_bf16(                           \
                af[r4][ks], bg[(ch)*4 + c4][ks],                               \
                acc[(rh)*4 + r4][(ch)*4 + c4], 0, 0, 0);                       \
  __builtin_amdgcn_s_setprio(0);                                               \
} while (0)

__global__ __launch_bounds__(256, 1) void k_gemm(const bf16* __restrict__ A,
                                                 const bf16* __restrict__ Bt,
                                                 float* __restrict__ partial) {
  // [buf][op 0=A 1=B][half of 128 rows][128*64] : 128 KiB
  __shared__ bf16 sm[2][2][2][128 * 64];
  int bid = blockIdx.x;
  int swz = (bid & 7) * 64 + (bid >> 3);     // 512 blocks, 8 XCDs, bijective
  int mt = swz & 31, nt = swz >> 5;
  int tid = threadIdx.x;
  int w = tid >> 6, lane = tid & 63;
  int wm = w >> 1, wn = w & 1;               // 2 x 2 wave grid, 128x128 each
  int lr = lane & 15, lk = lane >> 4;
  int r8 = lane >> 3, gg = lane & 7;
  int swcol = ((gg ^ r8) << 3);              // pre-swizzled source col (elems)
  size_t bm = (size_t)mt * 256, bn = (size_t)nt * 256;
  const bf16* Ab = A + bm * K_DIM;
  const bf16* Bb = Bt + bn * K_DIM;

  f32x4 acc[8][8] = {};
  bf16x8 af[4][2], bg[8][2];

  // stage one 64-row unit q of operand op at K-tile tt into buf:
  // 4 waves x 16 rows each (2 gloads of 8 rows each).
  auto STAGE_U = [&](int op, int q, int tt, int buf) {
    const bf16* g = (op == 0 ? Ab : Bb);
#pragma unroll
    for (int h8 = 0; h8 < 2; h8++) {
      int rowu = w * 16 + h8 * 8;            // row within the 64-row unit
      gload_lds16(g + (size_t)(q * 64 + rowu + r8) * K_DIM + tt * 64 + swcol,
                  &sm[buf][op][q >> 1][(q & 1) * 4096 + rowu * 64]);
    }
  };
  // swizzled fragment reads; row in 0..127 within this wave's half panel
  auto RDA = [&](int buf, int rb, int ks) -> bf16x8 {
    const bf16* h = &sm[buf][0][wm][0];
    int row = rb * 16 + lr;
    int gc = ks * 4 + lk;
    return *(const bf16x8*)(h + row * 64 + ((gc ^ (row & 7)) << 3));
  };
  auto RDB = [&](int buf, int cb, int ks) -> bf16x8 {
    const bf16* h = &sm[buf][1][wn][0];
    int row = cb * 16 + lr;
    int gc = ks * 4 + lk;
    return *(const bf16x8*)(h + row * 64 + ((gc ^ (row & 7)) << 3));
  };

  // prologue: t0 full (16 gloads) + t1 {A u0,u2; B v0-3} (12), FIFO order;
  // vmcnt(12)+BAR => all of t0 landed for ALL waves.
  STAGE_U(0, 0, 0, 0); STAGE_U(0, 2, 0, 0);
  STAGE_U(1, 0, 0, 0); STAGE_U(1, 1, 0, 0);
  STAGE_U(1, 2, 0, 0); STAGE_U(1, 3, 0, 0);
  STAGE_U(0, 1, 0, 0); STAGE_U(0, 3, 0, 0);
  STAGE_U(0, 0, 1, 1); STAGE_U(0, 2, 1, 1);
  STAGE_U(1, 0, 1, 1); STAGE_U(1, 1, 1, 1);
  STAGE_U(1, 2, 1, 1); STAGE_U(1, 3, 1, 1);
  ASM_VMCNT(12);
  BAR();

  for (int t = 0; t < NT; t++) {
    int cur = t & 1, nxt = cur ^ 1;
    int t1 = (t + 1 < NT) ? t + 1 : NT - 1;  // clamp keeps vmcnt FIFO uniform
    int t2 = (t + 2 < NT) ? t + 2 : NT - 1;

    // ---- phase 0: read af rb0-3 (u0/u2) + bg cb0-3 (v0/v2) ----
#pragma unroll
    for (int rb = 0; rb < 4; rb++) {
      af[rb][0] = RDA(cur, rb, 0);
      af[rb][1] = RDA(cur, rb, 1);
    }
#pragma unroll
    for (int cb = 0; cb < 4; cb++) {
      bg[cb][0] = RDB(cur, cb, 0);
      bg[cb][1] = RDB(cur, cb, 1);
    }
    STAGE_U(0, 1, t1, nxt); STAGE_U(0, 3, t1, nxt);  // A u1/u3 read @ph2 only
    BAR();
    MM(0, 0);
    BAR();

    // ---- phase 1: read bg cb4-7 (v1/v3) ----
#pragma unroll
    for (int cb = 4; cb < 8; cb++) {
      bg[cb][0] = RDB(cur, cb, 0);
      bg[cb][1] = RDB(cur, cb, 1);
    }
    STAGE_U(0, 0, t2, cur); STAGE_U(0, 2, t2, cur);  // A u0/u2 freed @ph0
    BAR();
    MM(0, 1);
    BAR();

    // ---- phase 2: read af rb4-7 (u1/u3) ----
#pragma unroll
    for (int rb = 0; rb < 4; rb++) {
      af[rb][0] = RDA(cur, 4 + rb, 0);
      af[rb][1] = RDA(cur, 4 + rb, 1);
    }
    STAGE_U(1, 0, t2, cur); STAGE_U(1, 1, t2, cur);  // B v0/v1 freed @ph0/ph1
    BAR();
    MM(1, 0);
    BAR();

    // ---- phase 3: no reads ----
    STAGE_U(1, 2, t2, cur); STAGE_U(1, 3, t2, cur);  // B v2/v3 freed @ph0/ph1
    BAR();
    MM(1, 1);
    // drain so all waves' tile-(t+1) loads are visible after the barrier;
    // 12 newest (ph1-ph3 stages, all for t+2) may stay in flight.
    ASM_VMCNT(12);
    BAR();
  }
  ASM_VMCNT(0);   // drain tail DMA before epilogue/endpgm

  // epilogue: per-row sum of squares over this wave's 128 cols
  // C frag: col = cb*16 + (lane&15), row = rb*16 + (lane>>4)*4 + reg
#pragma unroll
  for (int rb = 0; rb < 8; rb++) {
#pragma unroll
    for (int reg = 0; reg < 4; reg++) {
      float s = 0.f;
#pragma unroll
      for (int cb = 0; cb < 8; cb++) { float v = acc[rb][cb][reg]; s += v * v; }
      s += __shfl_xor(s, 1);
      s += __shfl_xor(s, 2);
      s += __shfl_xor(s, 4);
      s += __shfl_xor(s, 8);
      if (lr == 0) {
        int row = (int)bm + wm * 128 + rb * 16 + lk * 4 + reg;
        partial[(size_t)(nt * 2 + wn) * B_DIM + row] = s;
      }
    }
  }
}

// ---------------- finish: sum 32 partials per row, sqrt ----------------
__global__ void k_finish(const float* __restrict__ partial, float* __restrict__ out) {
  int b = blockIdx.x * 256 + threadIdx.x;
  float s = 0.f;
#pragma unroll
  for (int i = 0; i < 32; i++) s += partial[(size_t)i * B_DIM + b];
  out[b] = sqrtf(s);
}

extern "C" void kernel_launch(void* const* d_in, const int* in_sizes, int n_in,
                              void* d_out, int out_size, void* d_ws, size_t ws_size,
                              hipStream_t stream) {
  const float* x  = (const float*)d_in[0];
  const float* hw = (const float*)d_in[1];
  float* out = (float*)d_out;
  char* ws = (char*)d_ws;
  bf16* xb = (bf16*)ws;                                           // 64 MB
  bf16* wt = (bf16*)(ws + (size_t)B_DIM * K_DIM * 2);             // 32 MB
  float* partial = (float*)(ws + (size_t)B_DIM * K_DIM * 2
                               + (size_t)K_DIM * N_DIM * 2);      // 1 MB
  long long R[3];
  mt_randint3(1367u, R);

  k_convert_x<<<(B_DIM * K_DIM) / (256 * 8), 256, 0, stream>>>(x, xb);
  k_build_wt<<<(K_DIM / 32) * (N_DIM / 32), 256, 0, stream>>>(hw, wt, R[0], R[1], R[2]);
  k_gemm<<<(B_DIM / 256) * (N_DIM / 256), 256, 0, stream>>>(xb, wt, partial);
  k_finish<<<B_DIM / 256, 256, 0, stream>>>(partial, out);
}